// Round 7
// baseline (701.807 us; speedup 1.0000x reference)
//
#include <hip/hip_runtime.h>
#include <stdint.h>

// ---------------------------------------------------------------------------
// HierarchicalReasoningEncoder on MI355X (gfx950).
// fp32 I/O. R16: gru2 W-residency fix, take 2. R14 counters proved W_hh was
// never register-resident (VGPR=128 < 192 needed) — the compiler re-issues
// the 48 fragment loads every step (393 KB/CU/step from L2 ~= the whole
// 3000+ cy/step stall). R15's bf16x8 "+v" asm pins corrupted data (bf16
// vector inline-asm lowering bug). R16 pins each fragment as FOUR uint32
// scalar "+v" ties (well-tested path), then bit_casts to bf16x8: pure SSA,
// no address-taken locals, remat impossible. Everything else identical to
// R14. W-bf16 remains the only numerical approximation.
// ---------------------------------------------------------------------------

using uint32  = unsigned int;
using bf16x8  = __attribute__((ext_vector_type(8))) __bf16;
using floatx4 = __attribute__((ext_vector_type(4))) float;

__device__ __forceinline__ float b2f(unsigned short u) {
    union { uint32 i; float f; } v; v.i = ((uint32)u) << 16; return v.f;
}
__device__ __forceinline__ unsigned short f2b(float f) {
    union { float f; uint32 i; } v; v.f = f;
    uint32 r = v.i + 0x7fffu + ((v.i >> 16) & 1u);   // RNE
    return (unsigned short)(r >> 16);
}
__device__ __forceinline__ float sigmoidf_(float x) { return 1.f / (1.f + __expf(-x)); }
__device__ __forceinline__ float tanhf_(float x) {
    x = fminf(15.f, fmaxf(-15.f, x));
    float e = __expf(2.f * x);
    return (e - 1.f) / (e + 1.f);
}

// global -> LDS direct copy, 16 B per lane. LDS dest must be linear
// (base + lane*16); source address carries any swizzle.
__device__ __forceinline__ void gl16(const unsigned short* g, unsigned short* l) {
    __builtin_amdgcn_global_load_lds(
        (const __attribute__((address_space(1))) uint32*)g,
        (__attribute__((address_space(3))) uint32*)l, 16, 0, 0);
}

// lgkm-only barrier: waits LDS ops, does NOT touch vmcnt (global loads/
// stores stay in flight). sched_barrier(0) pins ordering (guide rule #18).
__device__ __forceinline__ void bar_lgkm() {
    asm volatile("s_waitcnt lgkmcnt(0)");
    __builtin_amdgcn_sched_barrier(0);
    __builtin_amdgcn_s_barrier();
    __builtin_amdgcn_sched_barrier(0);
}

// ---------------------------------------------------------------------------
// Workspace layout (bytes). Total ~197.8 MB.
// ---------------------------------------------------------------------------
#define O_XPC     0L            // 2*256*32*768*4 = 50331648 (chunked xp, fp32)
#define O_OWHI    50331648L     // 32768*512*2 = 33554432
#define O_OWLO    83886080L
#define O_STATE   117440512L    // 2*256*256*4 = 524288
#define O_SCW     117964800L    // 32768*4 = 131072
#define O_W0HI    118095872L
#define O_W0LO    118882304L
#define O_W1HI    119668736L
#define O_W1LO    120455168L
#define O_WAHI    121241600L
#define O_WALO    121765888L
#define O_S0HI    122290176L
#define O_S0LO    123076608L
#define O_S1HI    123863040L
#define O_S1LO    124649472L
#define O_SAHI    125435904L
#define O_SALO    125960192L
#define O_HW0     126484480L    // W_hh bf16 (393216 B each)
#define O_HW1     126877696L
#define O_HS0     127270912L
#define O_HS1     127664128L
#define O_SENTHI  128057344L
#define O_SENTLO  128319488L
#define O_XPS     128581632L    // 2*16*16*768*4 = 1572864
#define O_SSTATE  130154496L    // 2*16*256*4 = 32768
#define O_OSHI    130187264L
#define O_OSLO    130449408L
#define O_SCS     130711552L    // 1024
#define O_TKWH    130712576L    // 256*128*512*2 = 33554432 (full tok hi)
#define O_TKWL    164267008L    // 33554432 (full tok lo) -> end 197821440

// ---------------------------------------------------------------------------
// Weight prep: fp32 -> bf16 hi/lo, 6 matrices, one launch.
// ---------------------------------------------------------------------------
__global__ __launch_bounds__(256)
void cvt_hilo6(const float* __restrict__ s0, const float* __restrict__ s1,
               const float* __restrict__ s2, const float* __restrict__ s3,
               const float* __restrict__ s4, const float* __restrict__ s5,
               char* __restrict__ ws)
{
    const int b = blockIdx.x;
    const float* src; unsigned short *hi, *lo; int base;
    if (b < 192)      { src = s0; hi = (unsigned short*)(ws + O_W0HI); lo = (unsigned short*)(ws + O_W0LO); base = b; }
    else if (b < 384) { src = s1; hi = (unsigned short*)(ws + O_W1HI); lo = (unsigned short*)(ws + O_W1LO); base = b - 192; }
    else if (b < 576) { src = s2; hi = (unsigned short*)(ws + O_S0HI); lo = (unsigned short*)(ws + O_S0LO); base = b - 384; }
    else if (b < 768) { src = s3; hi = (unsigned short*)(ws + O_S1HI); lo = (unsigned short*)(ws + O_S1LO); base = b - 576; }
    else if (b < 896) { src = s4; hi = (unsigned short*)(ws + O_WAHI); lo = (unsigned short*)(ws + O_WALO); base = b - 768; }
    else              { src = s5; hi = (unsigned short*)(ws + O_SAHI); lo = (unsigned short*)(ws + O_SALO); base = b - 896; }
    const int idx = (base * 256 + threadIdx.x) * 8;
    float f[8];
    *reinterpret_cast<float4*>(&f[0]) = *reinterpret_cast<const float4*>(src + idx);
    *reinterpret_cast<float4*>(&f[4]) = *reinterpret_cast<const float4*>(src + idx + 4);
    unsigned short h[8], l[8];
    #pragma unroll
    for (int j = 0; j < 8; ++j) {
        h[j] = f2b(f[j]);
        l[j] = f2b(f[j] - b2f(h[j]));
    }
    *reinterpret_cast<uint4*>(hi + idx) = *reinterpret_cast<const uint4*>(h);
    *reinterpret_cast<uint4*>(lo + idx) = *reinterpret_cast<const uint4*>(l);
}

// W_hh fp32 -> single bf16, 4 matrices, one launch.
__global__ __launch_bounds__(256)
void cvt_b4(const float* __restrict__ s0, const float* __restrict__ s1,
            const float* __restrict__ s2, const float* __restrict__ s3,
            char* __restrict__ ws)
{
    const int b = blockIdx.x;
    const float* src; unsigned short* dst; int base;
    if (b < 96)       { src = s0; dst = (unsigned short*)(ws + O_HW0); base = b; }
    else if (b < 192) { src = s1; dst = (unsigned short*)(ws + O_HW1); base = b - 96; }
    else if (b < 288) { src = s2; dst = (unsigned short*)(ws + O_HS0); base = b - 192; }
    else              { src = s3; dst = (unsigned short*)(ws + O_HS1); base = b - 288; }
    const int idx = (base * 256 + threadIdx.x) * 8;
    float f[8];
    *reinterpret_cast<float4*>(&f[0]) = *reinterpret_cast<const float4*>(src + idx);
    *reinterpret_cast<float4*>(&f[4]) = *reinterpret_cast<const float4*>(src + idx + 4);
    unsigned short o[8];
    #pragma unroll
    for (int j = 0; j < 8; ++j) o[j] = f2b(f[j]);
    *reinterpret_cast<uint4*>(dst + idx) = *reinterpret_cast<const uint4*>(o);
}

// ---------------------------------------------------------------------------
// tok fp32 [2048 t'][16 b][512] -> bf16 hi/lo full buffer [256 seq][128 t][512]
// seq = b*16 + sent; t' = sent*128 + t.
// ---------------------------------------------------------------------------
__global__ __launch_bounds__(256)
void cvt_tokfull(const float* __restrict__ tok, unsigned short* __restrict__ whi,
                 unsigned short* __restrict__ wlo)
{
    const int u = blockIdx.x * 256 + threadIdx.x;     // 8192 blocks
    const int h8 = u & 63;
    const int rest = u >> 6;                          // seq*128 + t
    const int t = rest & 127, seq = rest >> 7;
    const int sent = seq & 15, b = seq >> 4;
    const long src = ((long)(sent * 128 + t) * 16 + b) * 512 + h8 * 8;
    float f[8];
    *reinterpret_cast<float4*>(&f[0]) = *reinterpret_cast<const float4*>(tok + src);
    *reinterpret_cast<float4*>(&f[4]) = *reinterpret_cast<const float4*>(tok + src + 4);
    unsigned short h[8], l[8];
    #pragma unroll
    for (int j = 0; j < 8; ++j) {
        h[j] = f2b(f[j]);
        l[j] = f2b(f[j] - b2f(h[j]));
    }
    const long dst = (long)rest * 512 + h8 * 8;
    *reinterpret_cast<uint4*>(whi + dst) = *reinterpret_cast<const uint4*>(h);
    *reinterpret_cast<uint4*>(wlo + dst) = *reinterpret_cast<const uint4*>(l);
}

// ---------------------------------------------------------------------------
// A-row remap (element offset, row length 512).
// AMODE 1: full tok buffer  (m = seq*32+tl -> row seq*128 + t0 + sgn*tl)
// AMODE 3: sentence         (m = b*16+tl  -> row b*16  + t0 + sgn*tl)
// AMODE 2: identity
// ---------------------------------------------------------------------------
template<int AMODE>
__device__ __forceinline__ long amap(int m, int t0, int sgn) {
    if (AMODE == 1) {
        const int sq = m >> 5, tl = m & 31;
        return (long)(sq * 128 + t0 + sgn * tl) * 512;
    } else if (AMODE == 3) {
        const int n = m >> 4, tl = m & 15;
        return (long)(n * 16 + t0 + sgn * tl) * 512;
    }
    return (long)m * 512;
}

// ---------------------------------------------------------------------------
// Big-tile GEMM (R14, unchanged): 256x256 tile, 8 waves (2M x 4N), per-wave
// 128x64. Single-barrier 2-phase schedule per K-step (BK=32):
//   stage(t+1) -> ds_read buf(t) -> lgkmcnt(0) -> MFMA x96 -> vmcnt(0)
//   -> s_barrier.
// ---------------------------------------------------------------------------
template<int AMODE, int OUT>
__global__ __launch_bounds__(512, 2)
void gemm_t(const unsigned short* __restrict__ Ahi, const unsigned short* __restrict__ Alo,
            const unsigned short* __restrict__ Wh0, const unsigned short* __restrict__ Wl0,
            const unsigned short* __restrict__ Wh1, const unsigned short* __restrict__ Wl1,
            const float* __restrict__ b0, const float* __restrict__ b1,
            float* __restrict__ C, int ldC, long c1off,
            float* __restrict__ score, const float* __restrict__ ctx,
            int t00, int t01, int nbyHalf)
{
    // 128 KB: 2 buffers x (Ahi 16K | Alo 16K | Whi 16K | Wlo 16K)
    __shared__ __align__(16) unsigned short smem[2 * 32768];

    int bx = blockIdx.x, by = blockIdx.y;
    {
        const int nbx = gridDim.x, nby = gridDim.y;
        if ((nby & 7) == 0) {
            const int l = by * nbx + bx;      // hardware-linear id (x fastest)
            const int xcd = l & 7;
            const int s = l >> 3;
            bx = s % nbx;
            by = xcd * (nby >> 3) + s / nbx;
        }
    }

    const int tid  = threadIdx.x;             // 0..511
    const int lane = tid & 63;
    const int wave = tid >> 6;                // 0..7
    const int wm = wave >> 2, wn = wave & 3;  // 2M x 4N
    const int n_base = bx * 256;
    const int q = lane >> 4;
    const int r = lane & 15;

    const unsigned short* Whi = Wh0;
    const unsigned short* Wlo = Wl0;
    const float* bias = b0;
    float* Cb = C;
    int t0 = t00, sgn = 1, m_base;
    if (nbyHalf > 0 && by >= nbyHalf) {
        Whi = Wh1; Wlo = Wl1; bias = b1; Cb = C + c1off;
        t0 = t01; sgn = -1;
        m_base = (by - nbyHalf) * 256;
    } else {
        m_base = by * 256;
    }

    // 1024 slots per subtile (256 rows x 4 k-chunks); 512 thr x 2 iters.
    long aoff[2], woff[2];
    #pragma unroll
    for (int i = 0; i < 2; ++i) {
        const int s = tid + 512 * i;
        const int R = s >> 2, kg = s & 3;
        const int kq = (kg - (R >> 1)) & 3;
        aoff[i] = amap<AMODE>(m_base + R, t0, sgn) + kq * 8;
        woff[i] = (long)(n_base + R) * 512 + kq * 8;
    }

    floatx4 acc[8][4];
    #pragma unroll
    for (int mt = 0; mt < 8; ++mt)
        #pragma unroll
        for (int nt = 0; nt < 4; ++nt) acc[mt][nt] = (floatx4){0.f, 0.f, 0.f, 0.f};

    // Stage K-step ts (BK=32) into buffer ts&1: 8 gl16 per thread.
    auto stage = [&](int ts) {
        const int k0 = ts * 32;
        unsigned short* B = smem + (ts & 1) * 32768;
        #pragma unroll
        for (int i = 0; i < 2; ++i) {
            const int ld = (tid + 512 * i) * 8;
            gl16(Ahi + aoff[i] + k0, B + ld);
            gl16(Alo + aoff[i] + k0, B + 8192 + ld);
            gl16(Whi + woff[i] + k0, B + 16384 + ld);
            gl16(Wlo + woff[i] + k0, B + 24576 + ld);
        }
    };

    // Prologue: stage buf0, drain once, sync.
    stage(0);
    asm volatile("s_waitcnt vmcnt(0)");
    __builtin_amdgcn_sched_barrier(0);
    __builtin_amdgcn_s_barrier();
    __builtin_amdgcn_sched_barrier(0);

    for (int t = 0; t < 16; ++t) {
        if (t + 1 < 16) stage(t + 1);   // into buf (t+1)&1 (freed last step)

        const unsigned short* B   = smem + (t & 1) * 32768;
        const unsigned short* BAl = B + 8192;
        const unsigned short* BW  = B + 16384;
        const unsigned short* BWl = B + 24576;

        bf16x8 wh[4], wl[4], ah[8], al[8];
        #pragma unroll
        for (int nt = 0; nt < 4; ++nt) {
            const int Rn = wn * 64 + nt * 16 + r;
            const int sn = Rn * 4 + ((q + (Rn >> 1)) & 3);
            wh[nt] = *reinterpret_cast<const bf16x8*>(BW  + sn * 8);
            wl[nt] = *reinterpret_cast<const bf16x8*>(BWl + sn * 8);
        }
        #pragma unroll
        for (int mt = 0; mt < 8; ++mt) {
            const int R = wm * 128 + mt * 16 + r;
            const int s = R * 4 + ((q + (R >> 1)) & 3);
            ah[mt] = *reinterpret_cast<const bf16x8*>(B   + s * 8);
            al[mt] = *reinterpret_cast<const bf16x8*>(BAl + s * 8);
        }
        asm volatile("s_waitcnt lgkmcnt(0)");
        __builtin_amdgcn_sched_barrier(0);

        #pragma unroll
        for (int mt = 0; mt < 8; ++mt)
            #pragma unroll
            for (int nt = 0; nt < 4; ++nt) {
                acc[mt][nt] = __builtin_amdgcn_mfma_f32_16x16x32_bf16(ah[mt], wh[nt], acc[mt][nt], 0, 0, 0);
                acc[mt][nt] = __builtin_amdgcn_mfma_f32_16x16x32_bf16(ah[mt], wl[nt], acc[mt][nt], 0, 0, 0);
                acc[mt][nt] = __builtin_amdgcn_mfma_f32_16x16x32_bf16(al[mt], wh[nt], acc[mt][nt], 0, 0, 0);
            }

        // Drain MY stage (issued a full MFMA-phase ago -> ~free), then sync.
        __builtin_amdgcn_sched_barrier(0);
        asm volatile("s_waitcnt vmcnt(0)");
        __builtin_amdgcn_sched_barrier(0);
        __builtin_amdgcn_s_barrier();
        __builtin_amdgcn_sched_barrier(0);
    }

    if (OUT == 0) {
        #pragma unroll
        for (int nt = 0; nt < 4; ++nt) {
            const int n = n_base + wn * 64 + nt * 16 + r;
            const float bs = bias[n];
            #pragma unroll
            for (int mt = 0; mt < 8; ++mt) {
                const int m = m_base + wm * 128 + mt * 16 + q * 4;
                #pragma unroll
                for (int e = 0; e < 4; ++e)
                    Cb[(long)(m + e) * ldC + n] = acc[mt][nt][e] + bs;
            }
        }
    } else {
        #pragma unroll
        for (int mt = 0; mt < 8; ++mt) {
            float p[4] = {0.f, 0.f, 0.f, 0.f};
            #pragma unroll
            for (int nt = 0; nt < 4; ++nt) {
                const int n = n_base + wn * 64 + nt * 16 + r;
                const float cx = ctx[n];
                const float bs = bias[n];
                #pragma unroll
                for (int e = 0; e < 4; ++e)
                    p[e] += cx * tanhf_(acc[mt][nt][e] + bs);
            }
            #pragma unroll
            for (int mk = 1; mk < 16; mk <<= 1) {
                #pragma unroll
                for (int e = 0; e < 4; ++e) p[e] += __shfl_xor(p[e], mk, 64);
            }
            if (r == 0) {
                const int m = m_base + wm * 128 + mt * 16 + q * 4;
                #pragma unroll
                for (int e = 0; e < 4; ++e)
                    atomicAdd(&score[m + e], p[e]);
            }
        }
    }
}

// ---------------------------------------------------------------------------
// Small GEMM (R12 structure, for sentence level): 128x128 tile, BK=32,
// 4 waves 2x2, 2-deep dbuf (64 KB), counted vmcnt(8). Unchanged (tiny cost).
// ---------------------------------------------------------------------------
template<int AMODE, int OUT>
__global__ __launch_bounds__(256)
void gemm_d(const unsigned short* __restrict__ Ahi, const unsigned short* __restrict__ Alo,
            const unsigned short* __restrict__ Wh0, const unsigned short* __restrict__ Wl0,
            const unsigned short* __restrict__ Wh1, const unsigned short* __restrict__ Wl1,
            const float* __restrict__ b0, const float* __restrict__ b1,
            float* __restrict__ C, int ldC, long c1off,
            float* __restrict__ score, const float* __restrict__ ctx,
            int t00, int t01, int nbyHalf)
{
    __shared__ __align__(16) unsigned short smem[2 * 16384];   // 64 KB

    int bx = blockIdx.x, by = blockIdx.y;
    {
        const int nbx = gridDim.x, nby = gridDim.y;
        if ((nby & 7) == 0) {
            const int l = by * nbx + bx;
            const int xcd = l & 7;
            const int s = l >> 3;
            bx = s % nbx;
            by = xcd * (nby >> 3) + s / nbx;
        }
    }

    const int tid  = threadIdx.x;
    const int lane = tid & 63;
    const int wave = tid >> 6;
    const int wm = wave >> 1, wn = wave & 1;
    const int n_base = bx * 128;
    const int q = lane >> 4;
    const int r = lane & 15;

    const unsigned short* Whi = Wh0;
    const unsigned short* Wlo = Wl0;
    const float* bias = b0;
    float* Cb = C;
    int t0 = t00, sgn = 1, m_base;
    if (nbyHalf > 0 && by >= nbyHalf) {
        Whi = Wh1; Wlo = Wl1; bias = b1; Cb = C + c1off;
        t0 = t01; sgn = -1;
        m_base = (by - nbyHalf) * 128;
    } else {
        m_base = by * 128;
    }

    long aoff[2], woff[2];
    #pragma unroll
    for (int i = 0; i < 2; ++i) {
        const int s = tid + 256 * i;
        const int R = s >> 2, kg = s & 3;
        const int kq = (kg - (R >> 1)) & 3;
        aoff[i] = amap<AMODE>(m_base + R, t0, sgn) + kq * 8;
        woff[i] = (long)(n_base + R) * 512 + kq * 8;
    }

    floatx4 acc[4][4];
    #pragma unroll
    for (int mt = 0; mt < 4; ++mt)
        #pragma unroll
        for (int nt = 0; nt < 4; ++nt) acc[mt][nt] = (floatx4){0.f, 0.f, 0.f, 0.f};

    auto stage = [&](int ts) {
        const int k0 = ts * 32;
        unsigned short* B = smem + (ts & 1) * 16384;
        #pragma unroll
        for (int i = 0; i < 2; ++i) {
            const int ld = (tid + 256 * i) * 8;
            gl16(Ahi + aoff[i] + k0, B + ld);
            gl16(Alo + aoff[i] + k0, B + 4096 + ld);
            gl16(Whi + woff[i] + k0, B + 8192 + ld);
            gl16(Wlo + woff[i] + k0, B + 12288 + ld);
        }
    };

    stage(0);
    for (int t = 0; t < 16; ++t) {
        stage(t + 1 < 16 ? t + 1 : 15);
        asm volatile("s_waitcnt vmcnt(8)\n\ts_barrier" ::: "memory");

        const unsigned short* B = smem + (t & 1) * 16384;
        bf16x8 ah[4], al[4];
        #pragma unroll
        for (int mt = 0; mt < 4; ++mt) {
            const int R = wm * 64 + mt * 16 + r;
            const int s = R * 4 + ((q + (R >> 1)) & 3);
            ah[mt] = *reinterpret_cast<const bf16x8*>(B + s * 8);
            al[mt] = *reinterpret_cast<const bf16x8*>(B + 4096 + s * 8);
        }
        #pragma unroll
        for (int nt = 0; nt < 4; ++nt) {
            const int Rn = wn * 64 + nt * 16 + r;
            const int sn = Rn * 4 + ((q + (Rn >> 1)) & 3);
            bf16x8 wh = *reinterpret_cast<const bf16x8*>(B + 8192 + sn * 8);
            bf16x8 wl = *reinterpret_cast<const bf16x8*>(B + 12288 + sn * 8);
            #pragma unroll
            for (int mt = 0; mt < 4; ++mt) {
                acc[mt][nt] = __builtin_amdgcn_mfma_f32_16x16x32_bf16(ah[mt], wh, acc[mt][nt], 0, 0, 0);
                acc[mt][nt] = __builtin_amdgcn_mfma_f32_16x16x32_bf16(ah[mt], wl, acc[mt][nt], 0, 0, 0);
                acc[mt][nt] = __builtin_amdgcn_mfma_f32_16x16x32_bf16(al[mt], wh, acc[mt][nt], 0, 0, 0);
            }
        }
        asm volatile("s_waitcnt lgkmcnt(0)\n\ts_barrier" ::: "memory");
    }
    asm volatile("s_waitcnt vmcnt(0)" ::: "memory");

    if (OUT == 0) {
        #pragma unroll
        for (int nt = 0; nt < 4; ++nt) {
            const int n = n_base + wn * 64 + nt * 16 + r;
            const float bs = bias[n];
            #pragma unroll
            for (int mt = 0; mt < 4; ++mt) {
                const int m = m_base + wm * 64 + mt * 16 + q * 4;
                #pragma unroll
                for (int e = 0; e < 4; ++e)
                    Cb[(long)(m + e) * ldC + n] = acc[mt][nt][e] + bs;
            }
        }
    } else {
        #pragma unroll
        for (int mt = 0; mt < 4; ++mt) {
            float p[4] = {0.f, 0.f, 0.f, 0.f};
            #pragma unroll
            for (int nt = 0; nt < 4; ++nt) {
                const int n = n_base + wn * 64 + nt * 16 + r;
                const float cx = ctx[n];
                const float bs = bias[n];
                #pragma unroll
                for (int e = 0; e < 4; ++e)
                    p[e] += cx * tanhf_(acc[mt][nt][e] + bs);
            }
            #pragma unroll
            for (int mk = 1; mk < 16; mk <<= 1) {
                #pragma unroll
                for (int e = 0; e < 4; ++e) p[e] += __shfl_xor(p[e], mk, 64);
            }
            if (r == 0) {
                const int m = m_base + wm * 64 + mt * 16 + q * 4;
                #pragma unroll
                for (int e = 0; e < 4; ++e)
                    atomicAdd(&score[m + e], p[e]);
            }
        }
    }
}

// ---------------------------------------------------------------------------
// GRU recurrence (R16): R14 structure; W_hh fragments loaded as uint4 and
// pinned live via four scalar uint32 "+v" asm ties (remat impossible, no
// bf16-vector asm operands), then bit_cast to bf16x8 for the MFMA.
// ---------------------------------------------------------------------------
__global__ __launch_bounds__(512, 2)
void gru2(const float* __restrict__ xp,
          const unsigned short* __restrict__ Wf,
          const unsigned short* __restrict__ Wb,
          const float* __restrict__ bhf, const float* __restrict__ bhb,
          float* __restrict__ state,
          unsigned short* __restrict__ ohi, unsigned short* __restrict__ olo,
          int steps, int t0f, int t0b, int groups, int Tout)
{
    __shared__ float pre[768 * 5];          // cols 0..3 at stride 5 (15360 B)
    __shared__ unsigned short Bf[8 * 64 * 8]; // B fragments (8192 B)

    const int tid  = threadIdx.x;
    const int lane = tid & 63;
    const int w    = tid >> 6;
    const int dir  = blockIdx.x / groups;
    const int g    = blockIdx.x % groups;
    const int nseq = groups * 2;
    const unsigned short* W = dir ? Wb : Wf;
    const float* bh = dir ? bhb : bhf;
    const int t0  = dir ? t0b : t0f;
    const int sgn = dir ? -1 : 1;

    const int s = tid >> 8;            // seq within WG (0..1)
    const int j = tid & 255;           // hidden unit
    const float bhr = bh[j], bhz = bh[j + 256], bhn = bh[j + 512];

    // --- W_hh fragments -> registers (rows w*96 .. w*96+95), pinned ---
    bf16x8 wf[6][8];
    {
        const int r0 = w * 96 + (lane & 15);
        const int kf = (lane >> 4) * 8;
        #pragma unroll
        for (int mt = 0; mt < 6; ++mt)
            #pragma unroll
            for (int kk = 0; kk < 8; ++kk) {
                uint4 t = *reinterpret_cast<const uint4*>(
                    W + (long)(r0 + mt * 16) * 256 + kk * 32 + kf);
                // Pin the four 32-bit components: asm "produces" opaque
                // values, so the load cannot be rematerialized in-loop.
                asm volatile("" : "+v"(t.x), "+v"(t.y), "+v"(t.z), "+v"(t.w));
                wf[mt][kk] = __builtin_bit_cast(bf16x8, t);
            }
    }

    // --- zero Bf (cols >=4 stay zero forever), init h ---
    #pragma unroll
    for (int i = 0; i < 4; ++i)
        reinterpret_cast<uint32*>(Bf)[tid * 4 + i] = 0;

    float h = state[((long)dir * nseq + g * 2 + s) * 256 + j];
    const int posHi = ((j >> 5) * 64 + ((j >> 3) & 3) * 16 + s) * 8 + (j & 7);
    const int posLo = ((j >> 5) * 64 + ((j >> 3) & 3) * 16 + 2 + s) * 8 + (j & 7);
    {
        const unsigned short hb = f2b(h);
        Bf[posHi] = hb;
        Bf[posLo] = f2b(h - b2f(hb));
    }
    bar_lgkm();

    const float* xbase = xp + (long)dir * nseq * steps * 768
                       + (long)(g * 2 + s) * steps * 768;
    const int q = lane >> 4, r = lane & 15;

    // step-0 x preload
    float xr = xbase[j], xz = xbase[256 + j], xn = xbase[512 + j];

    for (int st = 0; st < steps; ++st) {
        const int t = t0 + sgn * st;

        // ---- prefetch NEXT step's x (consumed next iteration) ----
        const int sn = (st + 1 < steps) ? st + 1 : st;
        const float* xb = xbase + (long)sn * 768;
        const float nxr = xb[j];
        const float nxz = xb[256 + j];
        const float nxn = xb[512 + j];

        // ---- MFMA phase: pre[row][0..3] = W_hh @ [h_hi | h_lo] ----
        floatx4 acc[6];
        #pragma unroll
        for (int mt = 0; mt < 6; ++mt) acc[mt] = (floatx4){0.f, 0.f, 0.f, 0.f};
        #pragma unroll
        for (int kk = 0; kk < 8; ++kk) {
            bf16x8 bv = *reinterpret_cast<const bf16x8*>(Bf + (kk * 64 + lane) * 8);
            #pragma unroll
            for (int mt = 0; mt < 6; ++mt)
                acc[mt] = __builtin_amdgcn_mfma_f32_16x16x32_bf16(wf[mt][kk], bv, acc[mt], 0, 0, 0);
        }
        if (r < 4) {
            #pragma unroll
            for (int mt = 0; mt < 6; ++mt) {
                const int row = w * 96 + mt * 16 + q * 4;
                #pragma unroll
                for (int e = 0; e < 4; ++e)
                    pre[(row + e) * 5 + r] = acc[mt][e];
            }
        }
        bar_lgkm();

        // ---- elementwise: one gate-triple per thread ----
        {
            const float pr = pre[j * 5 + s]         + pre[j * 5 + 2 + s];
            const float pz = pre[(j + 256) * 5 + s] + pre[(j + 256) * 5 + 2 + s];
            const float pn = pre[(j + 512) * 5 + s] + pre[(j + 512) * 5 + 2 + s];
            const float rg = sigmoidf_(xr + pr + bhr);
            const float zg = sigmoidf_(xz + pz + bhz);
            const float nn = tanhf_(xn + rg * (pn + bhn));
            h = (1.f - zg) * nn + zg * h;
            const unsigned short hb = f2b(h);
            const unsigned short lb = f2b(h - b2f(hb));
            Bf[posHi] = hb;
            Bf[posLo] = lb;
            const long orow = ((long)(g * 2 + s) * Tout + t) * 512 + dir * 256 + j;
            ohi[orow] = hb;
            olo[orow] = lb;
        }
        xr = nxr; xz = nxz; xn = nxn;
        bar_lgkm();
    }

    state[((long)dir * nseq + g * 2 + s) * 256 + j] = h;
}

// ---------------------------------------------------------------------------
// outv[n][:] = sum_t softmax(score[n*T..])_t * feats[n*T+t][:]  (H=512, fp32)
// ---------------------------------------------------------------------------
template<int MODE, int T>
__global__ __launch_bounds__(256)
void attn_wsum(const float* __restrict__ score,
               const unsigned short* __restrict__ fhi,
               const unsigned short* __restrict__ flo,
               void* __restrict__ o1, void* __restrict__ o2)
{
    const int n = blockIdx.x;
    const int tid = threadIdx.x;
    __shared__ float a[T];
    __shared__ float e[T];
    if (tid < T) a[tid] = score[n * T + tid];
    __syncthreads();
    float mx = -1e30f;
    #pragma unroll
    for (int t = 0; t < T; ++t) mx = fmaxf(mx, a[t]);
    if (tid < T) e[tid] = __expf(a[tid] - mx);
    __syncthreads();
    float sm = 0.f;
    #pragma unroll
    for (int t = 0; t < T; ++t) sm += e[t];
    const float inv = 1.f / sm;
    float acc0 = 0.f, acc1 = 0.f;
    #pragma unroll 8
    for (int t = 0; t < T; ++t) {
        const float w = e[t] * inv;
        const long base = ((long)n * T + t) * 512;
        acc0 += w * (b2f(fhi[base + tid])       + b2f(flo[base + tid]));
        acc1 += w * (b2f(fhi[base + tid + 256]) + b2f(flo[base + tid + 256]));
    }
    if (MODE == 1) {
        float* o = (float*)o1;
        o[n * 512 + tid] = acc0;
        o[n * 512 + tid + 256] = acc1;
    } else {
        unsigned short* oh = (unsigned short*)o1;
        unsigned short* ol = (unsigned short*)o2;
        const unsigned short h0 = f2b(acc0), h1 = f2b(acc1);
        oh[n * 512 + tid]       = h0;  ol[n * 512 + tid]       = f2b(acc0 - b2f(h0));
        oh[n * 512 + tid + 256] = h1;  ol[n * 512 + tid + 256] = f2b(acc1 - b2f(h1));
    }
}

extern "C" void kernel_launch(void* const* d_in, const int* in_sizes, int n_in,
                              void* d_out, int out_size, void* d_ws, size_t ws_size,
                              hipStream_t stream) {
    const float* tok      = (const float*)d_in[0];
    const float* w_wih_f  = (const float*)d_in[2];
    const float* w_whh_f  = (const float*)d_in[3];
    const float* w_bih_f  = (const float*)d_in[4];
    const float* w_bhh_f  = (const float*)d_in[5];
    const float* w_wih_b  = (const float*)d_in[6];
    const float* w_whh_b  = (const float*)d_in[7];
    const float* w_bih_b  = (const float*)d_in[8];
    const float* w_bhh_b  = (const float*)d_in[9];
    const float* s_wih_f  = (const float*)d_in[10];
    const float* s_whh_f  = (const float*)d_in[11];
    const float* s_bih_f  = (const float*)d_in[12];
    const float* s_bhh_f  = (const float*)d_in[13];
    const float* s_wih_b  = (const float*)d_in[14];
    const float* s_whh_b  = (const float*)d_in[15];
    const float* s_bih_b  = (const float*)d_in[16];
    const float* s_bhh_b  = (const float*)d_in[17];
    const float* w_attn_b = (const float*)d_in[19];
    const float* w_ctx    = (const float*)d_in[20];
    const float* s_attn_b = (const float*)d_in[22];
    const float* s_ctx    = (const float*)d_in[23];

    char* ws = (char*)d_ws;
    float*          xpc   = (float*)(ws + O_XPC);
    unsigned short* owhi  = (unsigned short*)(ws + O_OWHI);
    unsigned short* owlo  = (unsigned short*)(ws + O_OWLO);
    float*          state = (float*)(ws + O_STATE);
    float*          score_w = (float*)(ws + O_SCW);
    unsigned short* W0HI  = (unsigned short*)(ws + O_W0HI);
    unsigned short* W0LO  = (unsigned short*)(ws + O_W0LO);
    unsigned short* W1HI  = (unsigned short*)(ws + O_W1HI);
    unsigned short* W1LO  = (unsigned short*)(ws + O_W1LO);
    unsigned short* WAHI  = (unsigned short*)(ws + O_WAHI);
    unsigned short* WALO  = (unsigned short*)(ws + O_WALO);
    unsigned short* S0HI  = (unsigned short*)(ws + O_S0HI);
    unsigned short* S0LO  = (unsigned short*)(ws + O_S0LO);
    unsigned short* S1HI  = (unsigned short*)(ws + O_S1HI);
    unsigned short* S1LO  = (unsigned short*)(ws + O_S1LO);
    unsigned short* SAHI  = (unsigned short*)(ws + O_SAHI);
    unsigned short* SALO  = (unsigned short*)(ws + O_SALO);
    unsigned short* HW0   = (unsigned short*)(ws + O_HW0);
    unsigned short* HW1   = (unsigned short*)(ws + O_HW1);
    unsigned short* HS0   = (unsigned short*)(ws + O_HS0);
    unsigned short* HS1   = (unsigned short*)(ws + O_HS1);
    unsigned short* senthi = (unsigned short*)(ws + O_SENTHI);
    unsigned short* sentlo = (unsigned short*)(ws + O_SENTLO);
    float*          xp_s  = (float*)(ws + O_XPS);
    float*          sstate = (float*)(ws + O_SSTATE);
    unsigned short* oshi  = (unsigned short*)(ws + O_OSHI);
    unsigned short* oslo  = (unsigned short*)(ws + O_OSLO);
    float*          score_s = (float*)(ws + O_SCS);
    unsigned short* tkwh  = (unsigned short*)(ws + O_TKWH);
    unsigned short* tkwl  = (unsigned short*)(ws + O_TKWL);

    const dim3 blk(256);

    // Zero-init: GRU h states and atomic score accumulators.
    hipMemsetAsync(ws + O_STATE,  0, 524288, stream);
    hipMemsetAsync(ws + O_SSTATE, 0, 32768, stream);
    hipMemsetAsync(ws + O_SCW,    0, 131072, stream);
    hipMemsetAsync(ws + O_SCS,    0, 1024, stream);

    // Weight prep + full tok hi/lo split.
    cvt_hilo6<<<dim3(1024), blk, 0, stream>>>(w_wih_f, w_wih_b, s_wih_f, s_wih_b,
                                              (const float*)d_in[18], (const float*)d_in[21], ws);
    cvt_b4<<<dim3(384), blk, 0, stream>>>(w_whh_f, w_whh_b, s_whh_f, s_whh_b, ws);
    cvt_tokfull<<<dim3(8192), blk, 0, stream>>>(tok, tkwh, tkwl);

    // Word level: 4 time-chunks of 32 steps. Per chunk: one dual-direction
    // 256x256-tile GEMM (M=8192 x2 dirs, N=768 -> grid (3,64)), recurrence.
    const long XDW = 256L * 32 * 768;
    for (int c = 0; c < 4; ++c) {
        gemm_t<1, 0><<<dim3(3, 64), dim3(512), 0, stream>>>(
            tkwh, tkwl, W0HI, W0LO, W1HI, W1LO, w_bih_f, w_bih_b,
            xpc, 768, XDW, nullptr, nullptr, 32 * c, 127 - 32 * c, 32);
        gru2<<<dim3(256), dim3(512), 0, stream>>>(
            xpc, HW0, HW1, w_bhh_f, w_bhh_b, state, owhi, owlo,
            32, 32 * c, 127 - 32 * c, 128, 128);
    }

    // Word attention: fused u-GEMM + tanh·ctx score (M=32768, N=512 ->
    // grid (2,128) = 256 WGs), then softmax+wsum.
    gemm_t<2, 1><<<dim3(2, 128), dim3(512), 0, stream>>>(
        owhi, owlo, WAHI, WALO, WAHI, WALO, w_attn_b, w_attn_b,
        nullptr, 0, 0, score_w, w_ctx, 0, 0, 0);
    attn_wsum<0, 128><<<dim3(256), blk, 0, stream>>>(score_w, owhi, owlo, senthi, sentlo);

    // Sentence input gates: dual-direction, M=256, N=768 -> grid (6, 4).
    const long XDS = 16L * 16 * 768;
    gemm_d<3, 0><<<dim3(6, 4), blk, 0, stream>>>(
        senthi, sentlo, S0HI, S0LO, S1HI, S1LO, s_bih_f, s_bih_b,
        xp_s, 768, XDS, nullptr, nullptr, 0, 15, 2);

    // Sentence BiGRU: 16 seqs/dir, T=16; 2 seqs/WG -> grid 16.
    gru2<<<dim3(16), dim3(512), 0, stream>>>(
        xp_s, HS0, HS1, s_bhh_f, s_bhh_b, sstate, oshi, oslo,
        16, 0, 15, 8, 16);

    // Sentence attention -> d_out (16 x 512 fp32). M=256, N=512 -> (4, 2).
    gemm_d<2, 1><<<dim3(4, 2), blk, 0, stream>>>(
        oshi, oslo, SAHI, SALO, SAHI, SALO, s_attn_b, s_attn_b,
        nullptr, 0, 0, score_s, s_ctx, 0, 0, 0);
    attn_wsum<1, 16><<<dim3(16), blk, 0, stream>>>(score_s, oshi, oslo, d_out, nullptr);
}

// Round 8
// 678.101 us; speedup vs baseline: 1.0350x; 1.0350x over previous
//
#include <hip/hip_runtime.h>
#include <stdint.h>

// ---------------------------------------------------------------------------
// HierarchicalReasoningEncoder on MI355X (gfx950).
// fp32 I/O. R17: gru2 restructured for wave-locality. R16 falsified the
// W-residency theory (pins changed nothing -> W lives in AGPRs); the real
// stall is phase serialization: cross-wave pre exchange + 2 barriers/step.
// New partition: wave w owns units [w*32,w*32+32) for ALL 3 gates (6 tiles
// of 16 rows, same 48 MFMAs), so gate triples are produced and consumed
// within one wave: pre exchange = wave-private LDS (lgkm only, no barrier);
// h fragments go to a parity-double-buffered Bf -> ONE barrier per step.
// GEMMs/cvt/attn unchanged from R14. W-bf16 remains the only approximation.
// ---------------------------------------------------------------------------

using uint32  = unsigned int;
using bf16x8  = __attribute__((ext_vector_type(8))) __bf16;
using floatx4 = __attribute__((ext_vector_type(4))) float;

__device__ __forceinline__ float b2f(unsigned short u) {
    union { uint32 i; float f; } v; v.i = ((uint32)u) << 16; return v.f;
}
__device__ __forceinline__ unsigned short f2b(float f) {
    union { float f; uint32 i; } v; v.f = f;
    uint32 r = v.i + 0x7fffu + ((v.i >> 16) & 1u);   // RNE
    return (unsigned short)(r >> 16);
}
__device__ __forceinline__ float sigmoidf_(float x) { return 1.f / (1.f + __expf(-x)); }
__device__ __forceinline__ float tanhf_(float x) {
    x = fminf(15.f, fmaxf(-15.f, x));
    float e = __expf(2.f * x);
    return (e - 1.f) / (e + 1.f);
}

// global -> LDS direct copy, 16 B per lane. LDS dest must be linear
// (base + lane*16); source address carries any swizzle.
__device__ __forceinline__ void gl16(const unsigned short* g, unsigned short* l) {
    __builtin_amdgcn_global_load_lds(
        (const __attribute__((address_space(1))) uint32*)g,
        (__attribute__((address_space(3))) uint32*)l, 16, 0, 0);
}

// lgkm-only barrier: waits LDS ops, does NOT touch vmcnt (global loads/
// stores stay in flight). sched_barrier(0) pins ordering (guide rule #18).
__device__ __forceinline__ void bar_lgkm() {
    asm volatile("s_waitcnt lgkmcnt(0)");
    __builtin_amdgcn_sched_barrier(0);
    __builtin_amdgcn_s_barrier();
    __builtin_amdgcn_sched_barrier(0);
}

// ---------------------------------------------------------------------------
// Workspace layout (bytes). Total ~197.8 MB.
// ---------------------------------------------------------------------------
#define O_XPC     0L            // 2*256*32*768*4 = 50331648 (chunked xp, fp32)
#define O_OWHI    50331648L     // 32768*512*2 = 33554432
#define O_OWLO    83886080L
#define O_STATE   117440512L    // 2*256*256*4 = 524288
#define O_SCW     117964800L    // 32768*4 = 131072
#define O_W0HI    118095872L
#define O_W0LO    118882304L
#define O_W1HI    119668736L
#define O_W1LO    120455168L
#define O_WAHI    121241600L
#define O_WALO    121765888L
#define O_S0HI    122290176L
#define O_S0LO    123076608L
#define O_S1HI    123863040L
#define O_S1LO    124649472L
#define O_SAHI    125435904L
#define O_SALO    125960192L
#define O_HW0     126484480L    // W_hh bf16 (393216 B each)
#define O_HW1     126877696L
#define O_HS0     127270912L
#define O_HS1     127664128L
#define O_SENTHI  128057344L
#define O_SENTLO  128319488L
#define O_XPS     128581632L    // 2*16*16*768*4 = 1572864
#define O_SSTATE  130154496L    // 2*16*256*4 = 32768
#define O_OSHI    130187264L
#define O_OSLO    130449408L
#define O_SCS     130711552L    // 1024
#define O_TKWH    130712576L    // 256*128*512*2 = 33554432 (full tok hi)
#define O_TKWL    164267008L    // 33554432 (full tok lo) -> end 197821440

// ---------------------------------------------------------------------------
// Weight prep: fp32 -> bf16 hi/lo, 6 matrices, one launch.
// ---------------------------------------------------------------------------
__global__ __launch_bounds__(256)
void cvt_hilo6(const float* __restrict__ s0, const float* __restrict__ s1,
               const float* __restrict__ s2, const float* __restrict__ s3,
               const float* __restrict__ s4, const float* __restrict__ s5,
               char* __restrict__ ws)
{
    const int b = blockIdx.x;
    const float* src; unsigned short *hi, *lo; int base;
    if (b < 192)      { src = s0; hi = (unsigned short*)(ws + O_W0HI); lo = (unsigned short*)(ws + O_W0LO); base = b; }
    else if (b < 384) { src = s1; hi = (unsigned short*)(ws + O_W1HI); lo = (unsigned short*)(ws + O_W1LO); base = b - 192; }
    else if (b < 576) { src = s2; hi = (unsigned short*)(ws + O_S0HI); lo = (unsigned short*)(ws + O_S0LO); base = b - 384; }
    else if (b < 768) { src = s3; hi = (unsigned short*)(ws + O_S1HI); lo = (unsigned short*)(ws + O_S1LO); base = b - 576; }
    else if (b < 896) { src = s4; hi = (unsigned short*)(ws + O_WAHI); lo = (unsigned short*)(ws + O_WALO); base = b - 768; }
    else              { src = s5; hi = (unsigned short*)(ws + O_SAHI); lo = (unsigned short*)(ws + O_SALO); base = b - 896; }
    const int idx = (base * 256 + threadIdx.x) * 8;
    float f[8];
    *reinterpret_cast<float4*>(&f[0]) = *reinterpret_cast<const float4*>(src + idx);
    *reinterpret_cast<float4*>(&f[4]) = *reinterpret_cast<const float4*>(src + idx + 4);
    unsigned short h[8], l[8];
    #pragma unroll
    for (int j = 0; j < 8; ++j) {
        h[j] = f2b(f[j]);
        l[j] = f2b(f[j] - b2f(h[j]));
    }
    *reinterpret_cast<uint4*>(hi + idx) = *reinterpret_cast<const uint4*>(h);
    *reinterpret_cast<uint4*>(lo + idx) = *reinterpret_cast<const uint4*>(l);
}

// W_hh fp32 -> single bf16, 4 matrices, one launch.
__global__ __launch_bounds__(256)
void cvt_b4(const float* __restrict__ s0, const float* __restrict__ s1,
            const float* __restrict__ s2, const float* __restrict__ s3,
            char* __restrict__ ws)
{
    const int b = blockIdx.x;
    const float* src; unsigned short* dst; int base;
    if (b < 96)       { src = s0; dst = (unsigned short*)(ws + O_HW0); base = b; }
    else if (b < 192) { src = s1; dst = (unsigned short*)(ws + O_HW1); base = b - 96; }
    else if (b < 288) { src = s2; dst = (unsigned short*)(ws + O_HS0); base = b - 192; }
    else              { src = s3; dst = (unsigned short*)(ws + O_HS1); base = b - 288; }
    const int idx = (base * 256 + threadIdx.x) * 8;
    float f[8];
    *reinterpret_cast<float4*>(&f[0]) = *reinterpret_cast<const float4*>(src + idx);
    *reinterpret_cast<float4*>(&f[4]) = *reinterpret_cast<const float4*>(src + idx + 4);
    unsigned short o[8];
    #pragma unroll
    for (int j = 0; j < 8; ++j) o[j] = f2b(f[j]);
    *reinterpret_cast<uint4*>(dst + idx) = *reinterpret_cast<const uint4*>(o);
}

// ---------------------------------------------------------------------------
// tok fp32 [2048 t'][16 b][512] -> bf16 hi/lo full buffer [256 seq][128 t][512]
// seq = b*16 + sent; t' = sent*128 + t.
// ---------------------------------------------------------------------------
__global__ __launch_bounds__(256)
void cvt_tokfull(const float* __restrict__ tok, unsigned short* __restrict__ whi,
                 unsigned short* __restrict__ wlo)
{
    const int u = blockIdx.x * 256 + threadIdx.x;     // 8192 blocks
    const int h8 = u & 63;
    const int rest = u >> 6;                          // seq*128 + t
    const int t = rest & 127, seq = rest >> 7;
    const int sent = seq & 15, b = seq >> 4;
    const long src = ((long)(sent * 128 + t) * 16 + b) * 512 + h8 * 8;
    float f[8];
    *reinterpret_cast<float4*>(&f[0]) = *reinterpret_cast<const float4*>(tok + src);
    *reinterpret_cast<float4*>(&f[4]) = *reinterpret_cast<const float4*>(tok + src + 4);
    unsigned short h[8], l[8];
    #pragma unroll
    for (int j = 0; j < 8; ++j) {
        h[j] = f2b(f[j]);
        l[j] = f2b(f[j] - b2f(h[j]));
    }
    const long dst = (long)rest * 512 + h8 * 8;
    *reinterpret_cast<uint4*>(whi + dst) = *reinterpret_cast<const uint4*>(h);
    *reinterpret_cast<uint4*>(wlo + dst) = *reinterpret_cast<const uint4*>(l);
}

// ---------------------------------------------------------------------------
// A-row remap (element offset, row length 512).
// AMODE 1: full tok buffer  (m = seq*32+tl -> row seq*128 + t0 + sgn*tl)
// AMODE 3: sentence         (m = b*16+tl  -> row b*16  + t0 + sgn*tl)
// AMODE 2: identity
// ---------------------------------------------------------------------------
template<int AMODE>
__device__ __forceinline__ long amap(int m, int t0, int sgn) {
    if (AMODE == 1) {
        const int sq = m >> 5, tl = m & 31;
        return (long)(sq * 128 + t0 + sgn * tl) * 512;
    } else if (AMODE == 3) {
        const int n = m >> 4, tl = m & 15;
        return (long)(n * 16 + t0 + sgn * tl) * 512;
    }
    return (long)m * 512;
}

// ---------------------------------------------------------------------------
// Big-tile GEMM (R14, unchanged): 256x256 tile, 8 waves (2M x 4N), per-wave
// 128x64. Single-barrier 2-phase schedule per K-step (BK=32):
//   stage(t+1) -> ds_read buf(t) -> lgkmcnt(0) -> MFMA x96 -> vmcnt(0)
//   -> s_barrier.
// ---------------------------------------------------------------------------
template<int AMODE, int OUT>
__global__ __launch_bounds__(512, 2)
void gemm_t(const unsigned short* __restrict__ Ahi, const unsigned short* __restrict__ Alo,
            const unsigned short* __restrict__ Wh0, const unsigned short* __restrict__ Wl0,
            const unsigned short* __restrict__ Wh1, const unsigned short* __restrict__ Wl1,
            const float* __restrict__ b0, const float* __restrict__ b1,
            float* __restrict__ C, int ldC, long c1off,
            float* __restrict__ score, const float* __restrict__ ctx,
            int t00, int t01, int nbyHalf)
{
    // 128 KB: 2 buffers x (Ahi 16K | Alo 16K | Whi 16K | Wlo 16K)
    __shared__ __align__(16) unsigned short smem[2 * 32768];

    int bx = blockIdx.x, by = blockIdx.y;
    {
        const int nbx = gridDim.x, nby = gridDim.y;
        if ((nby & 7) == 0) {
            const int l = by * nbx + bx;      // hardware-linear id (x fastest)
            const int xcd = l & 7;
            const int s = l >> 3;
            bx = s % nbx;
            by = xcd * (nby >> 3) + s / nbx;
        }
    }

    const int tid  = threadIdx.x;             // 0..511
    const int lane = tid & 63;
    const int wave = tid >> 6;                // 0..7
    const int wm = wave >> 2, wn = wave & 3;  // 2M x 4N
    const int n_base = bx * 256;
    const int q = lane >> 4;
    const int r = lane & 15;

    const unsigned short* Whi = Wh0;
    const unsigned short* Wlo = Wl0;
    const float* bias = b0;
    float* Cb = C;
    int t0 = t00, sgn = 1, m_base;
    if (nbyHalf > 0 && by >= nbyHalf) {
        Whi = Wh1; Wlo = Wl1; bias = b1; Cb = C + c1off;
        t0 = t01; sgn = -1;
        m_base = (by - nbyHalf) * 256;
    } else {
        m_base = by * 256;
    }

    // 1024 slots per subtile (256 rows x 4 k-chunks); 512 thr x 2 iters.
    long aoff[2], woff[2];
    #pragma unroll
    for (int i = 0; i < 2; ++i) {
        const int s = tid + 512 * i;
        const int R = s >> 2, kg = s & 3;
        const int kq = (kg - (R >> 1)) & 3;
        aoff[i] = amap<AMODE>(m_base + R, t0, sgn) + kq * 8;
        woff[i] = (long)(n_base + R) * 512 + kq * 8;
    }

    floatx4 acc[8][4];
    #pragma unroll
    for (int mt = 0; mt < 8; ++mt)
        #pragma unroll
        for (int nt = 0; nt < 4; ++nt) acc[mt][nt] = (floatx4){0.f, 0.f, 0.f, 0.f};

    // Stage K-step ts (BK=32) into buffer ts&1: 8 gl16 per thread.
    auto stage = [&](int ts) {
        const int k0 = ts * 32;
        unsigned short* B = smem + (ts & 1) * 32768;
        #pragma unroll
        for (int i = 0; i < 2; ++i) {
            const int ld = (tid + 512 * i) * 8;
            gl16(Ahi + aoff[i] + k0, B + ld);
            gl16(Alo + aoff[i] + k0, B + 8192 + ld);
            gl16(Whi + woff[i] + k0, B + 16384 + ld);
            gl16(Wlo + woff[i] + k0, B + 24576 + ld);
        }
    };

    // Prologue: stage buf0, drain once, sync.
    stage(0);
    asm volatile("s_waitcnt vmcnt(0)");
    __builtin_amdgcn_sched_barrier(0);
    __builtin_amdgcn_s_barrier();
    __builtin_amdgcn_sched_barrier(0);

    for (int t = 0; t < 16; ++t) {
        if (t + 1 < 16) stage(t + 1);   // into buf (t+1)&1 (freed last step)

        const unsigned short* B   = smem + (t & 1) * 32768;
        const unsigned short* BAl = B + 8192;
        const unsigned short* BW  = B + 16384;
        const unsigned short* BWl = B + 24576;

        bf16x8 wh[4], wl[4], ah[8], al[8];
        #pragma unroll
        for (int nt = 0; nt < 4; ++nt) {
            const int Rn = wn * 64 + nt * 16 + r;
            const int sn = Rn * 4 + ((q + (Rn >> 1)) & 3);
            wh[nt] = *reinterpret_cast<const bf16x8*>(BW  + sn * 8);
            wl[nt] = *reinterpret_cast<const bf16x8*>(BWl + sn * 8);
        }
        #pragma unroll
        for (int mt = 0; mt < 8; ++mt) {
            const int R = wm * 128 + mt * 16 + r;
            const int s = R * 4 + ((q + (R >> 1)) & 3);
            ah[mt] = *reinterpret_cast<const bf16x8*>(B   + s * 8);
            al[mt] = *reinterpret_cast<const bf16x8*>(BAl + s * 8);
        }
        asm volatile("s_waitcnt lgkmcnt(0)");
        __builtin_amdgcn_sched_barrier(0);

        #pragma unroll
        for (int mt = 0; mt < 8; ++mt)
            #pragma unroll
            for (int nt = 0; nt < 4; ++nt) {
                acc[mt][nt] = __builtin_amdgcn_mfma_f32_16x16x32_bf16(ah[mt], wh[nt], acc[mt][nt], 0, 0, 0);
                acc[mt][nt] = __builtin_amdgcn_mfma_f32_16x16x32_bf16(ah[mt], wl[nt], acc[mt][nt], 0, 0, 0);
                acc[mt][nt] = __builtin_amdgcn_mfma_f32_16x16x32_bf16(al[mt], wh[nt], acc[mt][nt], 0, 0, 0);
            }

        // Drain MY stage (issued a full MFMA-phase ago -> ~free), then sync.
        __builtin_amdgcn_sched_barrier(0);
        asm volatile("s_waitcnt vmcnt(0)");
        __builtin_amdgcn_sched_barrier(0);
        __builtin_amdgcn_s_barrier();
        __builtin_amdgcn_sched_barrier(0);
    }

    if (OUT == 0) {
        #pragma unroll
        for (int nt = 0; nt < 4; ++nt) {
            const int n = n_base + wn * 64 + nt * 16 + r;
            const float bs = bias[n];
            #pragma unroll
            for (int mt = 0; mt < 8; ++mt) {
                const int m = m_base + wm * 128 + mt * 16 + q * 4;
                #pragma unroll
                for (int e = 0; e < 4; ++e)
                    Cb[(long)(m + e) * ldC + n] = acc[mt][nt][e] + bs;
            }
        }
    } else {
        #pragma unroll
        for (int mt = 0; mt < 8; ++mt) {
            float p[4] = {0.f, 0.f, 0.f, 0.f};
            #pragma unroll
            for (int nt = 0; nt < 4; ++nt) {
                const int n = n_base + wn * 64 + nt * 16 + r;
                const float cx = ctx[n];
                const float bs = bias[n];
                #pragma unroll
                for (int e = 0; e < 4; ++e)
                    p[e] += cx * tanhf_(acc[mt][nt][e] + bs);
            }
            #pragma unroll
            for (int mk = 1; mk < 16; mk <<= 1) {
                #pragma unroll
                for (int e = 0; e < 4; ++e) p[e] += __shfl_xor(p[e], mk, 64);
            }
            if (r == 0) {
                const int m = m_base + wm * 128 + mt * 16 + q * 4;
                #pragma unroll
                for (int e = 0; e < 4; ++e)
                    atomicAdd(&score[m + e], p[e]);
            }
        }
    }
}

// ---------------------------------------------------------------------------
// Small GEMM (R12 structure, for sentence level): 128x128 tile, BK=32,
// 4 waves 2x2, 2-deep dbuf (64 KB), counted vmcnt(8). Unchanged (tiny cost).
// ---------------------------------------------------------------------------
template<int AMODE, int OUT>
__global__ __launch_bounds__(256)
void gemm_d(const unsigned short* __restrict__ Ahi, const unsigned short* __restrict__ Alo,
            const unsigned short* __restrict__ Wh0, const unsigned short* __restrict__ Wl0,
            const unsigned short* __restrict__ Wh1, const unsigned short* __restrict__ Wl1,
            const float* __restrict__ b0, const float* __restrict__ b1,
            float* __restrict__ C, int ldC, long c1off,
            float* __restrict__ score, const float* __restrict__ ctx,
            int t00, int t01, int nbyHalf)
{
    __shared__ __align__(16) unsigned short smem[2 * 16384];   // 64 KB

    int bx = blockIdx.x, by = blockIdx.y;
    {
        const int nbx = gridDim.x, nby = gridDim.y;
        if ((nby & 7) == 0) {
            const int l = by * nbx + bx;
            const int xcd = l & 7;
            const int s = l >> 3;
            bx = s % nbx;
            by = xcd * (nby >> 3) + s / nbx;
        }
    }

    const int tid  = threadIdx.x;
    const int lane = tid & 63;
    const int wave = tid >> 6;
    const int wm = wave >> 1, wn = wave & 1;
    const int n_base = bx * 128;
    const int q = lane >> 4;
    const int r = lane & 15;

    const unsigned short* Whi = Wh0;
    const unsigned short* Wlo = Wl0;
    const float* bias = b0;
    float* Cb = C;
    int t0 = t00, sgn = 1, m_base;
    if (nbyHalf > 0 && by >= nbyHalf) {
        Whi = Wh1; Wlo = Wl1; bias = b1; Cb = C + c1off;
        t0 = t01; sgn = -1;
        m_base = (by - nbyHalf) * 128;
    } else {
        m_base = by * 128;
    }

    long aoff[2], woff[2];
    #pragma unroll
    for (int i = 0; i < 2; ++i) {
        const int s = tid + 256 * i;
        const int R = s >> 2, kg = s & 3;
        const int kq = (kg - (R >> 1)) & 3;
        aoff[i] = amap<AMODE>(m_base + R, t0, sgn) + kq * 8;
        woff[i] = (long)(n_base + R) * 512 + kq * 8;
    }

    floatx4 acc[4][4];
    #pragma unroll
    for (int mt = 0; mt < 4; ++mt)
        #pragma unroll
        for (int nt = 0; nt < 4; ++nt) acc[mt][nt] = (floatx4){0.f, 0.f, 0.f, 0.f};

    auto stage = [&](int ts) {
        const int k0 = ts * 32;
        unsigned short* B = smem + (ts & 1) * 16384;
        #pragma unroll
        for (int i = 0; i < 2; ++i) {
            const int ld = (tid + 256 * i) * 8;
            gl16(Ahi + aoff[i] + k0, B + ld);
            gl16(Alo + aoff[i] + k0, B + 4096 + ld);
            gl16(Whi + woff[i] + k0, B + 8192 + ld);
            gl16(Wlo + woff[i] + k0, B + 12288 + ld);
        }
    };

    stage(0);
    for (int t = 0; t < 16; ++t) {
        stage(t + 1 < 16 ? t + 1 : 15);
        asm volatile("s_waitcnt vmcnt(8)\n\ts_barrier" ::: "memory");

        const unsigned short* B = smem + (t & 1) * 16384;
        bf16x8 ah[4], al[4];
        #pragma unroll
        for (int mt = 0; mt < 4; ++mt) {
            const int R = wm * 64 + mt * 16 + r;
            const int s = R * 4 + ((q + (R >> 1)) & 3);
            ah[mt] = *reinterpret_cast<const bf16x8*>(B + s * 8);
            al[mt] = *reinterpret_cast<const bf16x8*>(B + 4096 + s * 8);
        }
        #pragma unroll
        for (int nt = 0; nt < 4; ++nt) {
            const int Rn = wn * 64 + nt * 16 + r;
            const int sn = Rn * 4 + ((q + (Rn >> 1)) & 3);
            bf16x8 wh = *reinterpret_cast<const bf16x8*>(B + 8192 + sn * 8);
            bf16x8 wl = *reinterpret_cast<const bf16x8*>(B + 12288 + sn * 8);
            #pragma unroll
            for (int mt = 0; mt < 4; ++mt) {
                acc[mt][nt] = __builtin_amdgcn_mfma_f32_16x16x32_bf16(ah[mt], wh, acc[mt][nt], 0, 0, 0);
                acc[mt][nt] = __builtin_amdgcn_mfma_f32_16x16x32_bf16(ah[mt], wl, acc[mt][nt], 0, 0, 0);
                acc[mt][nt] = __builtin_amdgcn_mfma_f32_16x16x32_bf16(al[mt], wh, acc[mt][nt], 0, 0, 0);
            }
        }
        asm volatile("s_waitcnt lgkmcnt(0)\n\ts_barrier" ::: "memory");
    }
    asm volatile("s_waitcnt vmcnt(0)" ::: "memory");

    if (OUT == 0) {
        #pragma unroll
        for (int nt = 0; nt < 4; ++nt) {
            const int n = n_base + wn * 64 + nt * 16 + r;
            const float bs = bias[n];
            #pragma unroll
            for (int mt = 0; mt < 4; ++mt) {
                const int m = m_base + wm * 64 + mt * 16 + q * 4;
                #pragma unroll
                for (int e = 0; e < 4; ++e)
                    Cb[(long)(m + e) * ldC + n] = acc[mt][nt][e] + bs;
            }
        }
    } else {
        #pragma unroll
        for (int mt = 0; mt < 4; ++mt) {
            float p[4] = {0.f, 0.f, 0.f, 0.f};
            #pragma unroll
            for (int nt = 0; nt < 4; ++nt) {
                const int n = n_base + wn * 64 + nt * 16 + r;
                const float cx = ctx[n];
                const float bs = bias[n];
                #pragma unroll
                for (int e = 0; e < 4; ++e)
                    p[e] += cx * tanhf_(acc[mt][nt][e] + bs);
            }
            #pragma unroll
            for (int mk = 1; mk < 16; mk <<= 1) {
                #pragma unroll
                for (int e = 0; e < 4; ++e) p[e] += __shfl_xor(p[e], mk, 64);
            }
            if (r == 0) {
                const int m = m_base + wm * 64 + mt * 16 + q * 4;
                #pragma unroll
                for (int e = 0; e < 4; ++e)
                    atomicAdd(&score[m + e], p[e]);
            }
        }
    }
}

// ---------------------------------------------------------------------------
// GRU recurrence (R17): wave-local partition. Wave w owns hidden units
// U(w) = [w*32, w*32+32) for all 3 gates: 6 A-tiles of 16 rows
// (rows (mt>>1)*256 + w*32 + (mt&1)*16), 48 MFMAs/wave/step as before.
// Post-MFMA: wave writes its cols 0..3 into a wave-PRIVATE preS region
// (lgkm wait only — no barrier), reads back gate triples as float4, does
// the elementwise for its own 64 (u,s) pairs, writes h into parity-double-
// buffered Bf[nxt]. ONE s_barrier per step (Bf cross-wave handoff).
// Thread map: lane -> (s = lane&1, u = w*32 + (lane>>1)).
// ---------------------------------------------------------------------------
__global__ __launch_bounds__(512, 2)
void gru2(const float* __restrict__ xp,
          const unsigned short* __restrict__ Wf,
          const unsigned short* __restrict__ Wb,
          const float* __restrict__ bhf, const float* __restrict__ bhb,
          float* __restrict__ state,
          unsigned short* __restrict__ ohi, unsigned short* __restrict__ olo,
          int steps, int t0f, int t0b, int groups, int Tout)
{
    __shared__ float preS[8][6][16][4];          // 12288 B, wave-private [w]
    __shared__ unsigned short Bf[2][4096];       // 2 x 8192 B, step parity

    const int tid  = threadIdx.x;
    const int lane = tid & 63;
    const int w    = tid >> 6;
    const int dir  = blockIdx.x / groups;
    const int g    = blockIdx.x % groups;
    const int nseq = groups * 2;
    const unsigned short* W = dir ? Wb : Wf;
    const float* bh = dir ? bhb : bhf;
    const int t0  = dir ? t0b : t0f;
    const int sgn = dir ? -1 : 1;

    const int s  = lane & 1;            // seq within WG
    const int lr = lane >> 1;           // 0..31: unit within wave's slice
    const int u  = w * 32 + lr;         // hidden unit (0..255)

    const float bhr = bh[u], bhz = bh[u + 256], bhn = bh[u + 512];

    // --- W_hh fragments: wave w's 6 tiles (3 gates x 2 half-slices) ---
    bf16x8 wf[6][8];
    {
        const int rl = lane & 15;
        const int kf = (lane >> 4) * 8;
        #pragma unroll
        for (int mt = 0; mt < 6; ++mt) {
            const int R = (mt >> 1) * 256 + w * 32 + (mt & 1) * 16 + rl;
            #pragma unroll
            for (int kk = 0; kk < 8; ++kk)
                wf[mt][kk] = *reinterpret_cast<const bf16x8*>(
                    W + (long)R * 256 + kk * 32 + kf);
        }
    }

    // --- zero both Bf buffers (cols >=4 stay zero forever), init h ---
    #pragma unroll
    for (int i = 0; i < 8; ++i)
        reinterpret_cast<uint32*>(Bf)[tid * 8 + i] = 0;

    float h = state[((long)dir * nseq + g * 2 + s) * 256 + u];
    // Bf slot for (u, s): region kk=w, lane (lr>>3)*16 + col, elem lr&7.
    const int bposHi = (w * 64 + (lr >> 3) * 16 + s) * 8 + (lr & 7);
    const int bposLo = (w * 64 + (lr >> 3) * 16 + 2 + s) * 8 + (lr & 7);
    {
        const unsigned short hb = f2b(h);
        Bf[0][bposHi] = hb;
        Bf[0][bposLo] = f2b(h - b2f(hb));
    }
    bar_lgkm();

    const float* xbase = xp + (long)dir * nseq * steps * 768
                       + (long)(g * 2 + s) * steps * 768;

    // step-0 x preload
    float xr = xbase[u], xz = xbase[256 + u], xn = xbase[512 + u];

    const int c  = lane & 15;           // output col held by this lane
    const int q  = lane >> 4;           // output row-group
    const int rit  = lr & 15;           // row within 16-row tile
    const int hsel = lr >> 4;           // which half-slice tile

    for (int st = 0; st < steps; ++st) {
        const int t = t0 + sgn * st;
        const int cur = st & 1;

        // ---- prefetch NEXT step's x (consumed next iteration) ----
        const int sn2 = (st + 1 < steps) ? st + 1 : st;
        const float* xb = xbase + (long)sn2 * 768;
        const float nxr = xb[u];
        const float nxz = xb[256 + u];
        const float nxn = xb[512 + u];

        // ---- MFMA: acc[mt] = W(rows of tile mt) @ [h_hi | h_lo] ----
        floatx4 acc[6];
        #pragma unroll
        for (int mt = 0; mt < 6; ++mt) acc[mt] = (floatx4){0.f, 0.f, 0.f, 0.f};
        #pragma unroll
        for (int kk = 0; kk < 8; ++kk) {
            bf16x8 bv = *reinterpret_cast<const bf16x8*>(&Bf[cur][(kk * 64 + lane) * 8]);
            #pragma unroll
            for (int mt = 0; mt < 6; ++mt)
                acc[mt] = __builtin_amdgcn_mfma_f32_16x16x32_bf16(wf[mt][kk], bv, acc[mt], 0, 0, 0);
        }

        // ---- wave-private exchange: cols 0..3 -> preS[w] (no barrier) ----
        if (c < 4) {
            #pragma unroll
            for (int mt = 0; mt < 6; ++mt)
                #pragma unroll
                for (int e = 0; e < 4; ++e)
                    preS[w][mt][q * 4 + e][c] = acc[mt][e];
        }
        asm volatile("s_waitcnt lgkmcnt(0)");
        __builtin_amdgcn_sched_barrier(0);

        // ---- elementwise for (u, s): gate triples from own wave ----
        {
            const float4 fr = *reinterpret_cast<const float4*>(&preS[w][0 + hsel][rit][0]);
            const float4 fz = *reinterpret_cast<const float4*>(&preS[w][2 + hsel][rit][0]);
            const float4 fn = *reinterpret_cast<const float4*>(&preS[w][4 + hsel][rit][0]);
            const float pr = (s ? fr.y : fr.x) + (s ? fr.w : fr.z);
            const float pz = (s ? fz.y : fz.x) + (s ? fz.w : fz.z);
            const float pn = (s ? fn.y : fn.x) + (s ? fn.w : fn.z);
            const float rg = sigmoidf_(xr + pr + bhr);
            const float zg = sigmoidf_(xz + pz + bhz);
            const float nn = tanhf_(xn + rg * (pn + bhn));
            h = (1.f - zg) * nn + zg * h;
            const unsigned short hb = f2b(h);
            const unsigned short lb = f2b(h - b2f(hb));
            Bf[cur ^ 1][bposHi] = hb;
            Bf[cur ^ 1][bposLo] = lb;
            const long orow = ((long)(g * 2 + s) * Tout + t) * 512 + dir * 256 + u;
            ohi[orow] = hb;
            olo[orow] = lb;
        }
        xr = nxr; xz = nxz; xn = nxn;
        bar_lgkm();   // ONE barrier/step: Bf[nxt] ready for all waves
    }

    state[((long)dir * nseq + g * 2 + s) * 256 + u] = h;
}

// ---------------------------------------------------------------------------
// outv[n][:] = sum_t softmax(score[n*T..])_t * feats[n*T+t][:]  (H=512, fp32)
// ---------------------------------------------------------------------------
template<int MODE, int T>
__global__ __launch_bounds__(256)
void attn_wsum(const float* __restrict__ score,
               const unsigned short* __restrict__ fhi,
               const unsigned short* __restrict__ flo,
               void* __restrict__ o1, void* __restrict__ o2)
{
    const int n = blockIdx.x;
    const int tid = threadIdx.x;
    __shared__ float a[T];
    __shared__ float e[T];
    if (tid < T) a[tid] = score[n * T + tid];
    __syncthreads();
    float mx = -1e30f;
    #pragma unroll
    for (int t = 0; t < T; ++t) mx = fmaxf(mx, a[t]);
    if (tid < T) e[tid] = __expf(a[tid] - mx);
    __syncthreads();
    float sm = 0.f;
    #pragma unroll
    for (int t = 0; t < T; ++t) sm += e[t];
    const float inv = 1.f / sm;
    float acc0 = 0.f, acc1 = 0.f;
    #pragma unroll 8
    for (int t = 0; t < T; ++t) {
        const float w = e[t] * inv;
        const long base = ((long)n * T + t) * 512;
        acc0 += w * (b2f(fhi[base + tid])       + b2f(flo[base + tid]));
        acc1 += w * (b2f(fhi[base + tid + 256]) + b2f(flo[base + tid + 256]));
    }
    if (MODE == 1) {
        float* o = (float*)o1;
        o[n * 512 + tid] = acc0;
        o[n * 512 + tid + 256] = acc1;
    } else {
        unsigned short* oh = (unsigned short*)o1;
        unsigned short* ol = (unsigned short*)o2;
        const unsigned short h0 = f2b(acc0), h1 = f2b(acc1);
        oh[n * 512 + tid]       = h0;  ol[n * 512 + tid]       = f2b(acc0 - b2f(h0));
        oh[n * 512 + tid + 256] = h1;  ol[n * 512 + tid + 256] = f2b(acc1 - b2f(h1));
    }
}

extern "C" void kernel_launch(void* const* d_in, const int* in_sizes, int n_in,
                              void* d_out, int out_size, void* d_ws, size_t ws_size,
                              hipStream_t stream) {
    const float* tok      = (const float*)d_in[0];
    const float* w_wih_f  = (const float*)d_in[2];
    const float* w_whh_f  = (const float*)d_in[3];
    const float* w_bih_f  = (const float*)d_in[4];
    const float* w_bhh_f  = (const float*)d_in[5];
    const float* w_wih_b  = (const float*)d_in[6];
    const float* w_whh_b  = (const float*)d_in[7];
    const float* w_bih_b  = (const float*)d_in[8];
    const float* w_bhh_b  = (const float*)d_in[9];
    const float* s_wih_f  = (const float*)d_in[10];
    const float* s_whh_f  = (const float*)d_in[11];
    const float* s_bih_f  = (const float*)d_in[12];
    const float* s_bhh_f  = (const float*)d_in[13];
    const float* s_wih_b  = (const float*)d_in[14];
    const float* s_whh_b  = (const float*)d_in[15];
    const float* s_bih_b  = (const float*)d_in[16];
    const float* s_bhh_b  = (const float*)d_in[17];
    const float* w_attn_b = (const float*)d_in[19];
    const float* w_ctx    = (const float*)d_in[20];
    const float* s_attn_b = (const float*)d_in[22];
    const float* s_ctx    = (const float*)d_in[23];

    char* ws = (char*)d_ws;
    float*          xpc   = (float*)(ws + O_XPC);
    unsigned short* owhi  = (unsigned short*)(ws + O_OWHI);
    unsigned short* owlo  = (unsigned short*)(ws + O_OWLO);
    float*          state = (float*)(ws + O_STATE);
    float*          score_w = (float*)(ws + O_SCW);
    unsigned short* W0HI  = (unsigned short*)(ws + O_W0HI);
    unsigned short* W0LO  = (unsigned short*)(ws + O_W0LO);
    unsigned short* W1HI  = (unsigned short*)(ws + O_W1HI);
    unsigned short* W1LO  = (unsigned short*)(ws + O_W1LO);
    unsigned short* WAHI  = (unsigned short*)(ws + O_WAHI);
    unsigned short* WALO  = (unsigned short*)(ws + O_WALO);
    unsigned short* S0HI  = (unsigned short*)(ws + O_S0HI);
    unsigned short* S0LO  = (unsigned short*)(ws + O_S0LO);
    unsigned short* S1HI  = (unsigned short*)(ws + O_S1HI);
    unsigned short* S1LO  = (unsigned short*)(ws + O_S1LO);
    unsigned short* SAHI  = (unsigned short*)(ws + O_SAHI);
    unsigned short* SALO  = (unsigned short*)(ws + O_SALO);
    unsigned short* HW0   = (unsigned short*)(ws + O_HW0);
    unsigned short* HW1   = (unsigned short*)(ws + O_HW1);
    unsigned short* HS0   = (unsigned short*)(ws + O_HS0);
    unsigned short* HS1   = (unsigned short*)(ws + O_HS1);
    unsigned short* senthi = (unsigned short*)(ws + O_SENTHI);
    unsigned short* sentlo = (unsigned short*)(ws + O_SENTLO);
    float*          xp_s  = (float*)(ws + O_XPS);
    float*          sstate = (float*)(ws + O_SSTATE);
    unsigned short* oshi  = (unsigned short*)(ws + O_OSHI);
    unsigned short* oslo  = (unsigned short*)(ws + O_OSLO);
    float*          score_s = (float*)(ws + O_SCS);
    unsigned short* tkwh  = (unsigned short*)(ws + O_TKWH);
    unsigned short* tkwl  = (unsigned short*)(ws + O_TKWL);

    const dim3 blk(256);

    // Zero-init: GRU h states and atomic score accumulators.
    hipMemsetAsync(ws + O_STATE,  0, 524288, stream);
    hipMemsetAsync(ws + O_SSTATE, 0, 32768, stream);
    hipMemsetAsync(ws + O_SCW,    0, 131072, stream);
    hipMemsetAsync(ws + O_SCS,    0, 1024, stream);

    // Weight prep + full tok hi/lo split.
    cvt_hilo6<<<dim3(1024), blk, 0, stream>>>(w_wih_f, w_wih_b, s_wih_f, s_wih_b,
                                              (const float*)d_in[18], (const float*)d_in[21], ws);
    cvt_b4<<<dim3(384), blk, 0, stream>>>(w_whh_f, w_whh_b, s_whh_f, s_whh_b, ws);
    cvt_tokfull<<<dim3(8192), blk, 0, stream>>>(tok, tkwh, tkwl);

    // Word level: 4 time-chunks of 32 steps. Per chunk: one dual-direction
    // 256x256-tile GEMM (M=8192 x2 dirs, N=768 -> grid (3,64)), recurrence.
    const long XDW = 256L * 32 * 768;
    for (int c = 0; c < 4; ++c) {
        gemm_t<1, 0><<<dim3(3, 64), dim3(512), 0, stream>>>(
            tkwh, tkwl, W0HI, W0LO, W1HI, W1LO, w_bih_f, w_bih_b,
            xpc, 768, XDW, nullptr, nullptr, 32 * c, 127 - 32 * c, 32);
        gru2<<<dim3(256), dim3(512), 0, stream>>>(
            xpc, HW0, HW1, w_bhh_f, w_bhh_b, state, owhi, owlo,
            32, 32 * c, 127 - 32 * c, 128, 128);
    }

    // Word attention: fused u-GEMM + tanh·ctx score (M=32768, N=512 ->
    // grid (2,128) = 256 WGs), then softmax+wsum.
    gemm_t<2, 1><<<dim3(2, 128), dim3(512), 0, stream>>>(
        owhi, owlo, WAHI, WALO, WAHI, WALO, w_attn_b, w_attn_b,
        nullptr, 0, 0, score_w, w_ctx, 0, 0, 0);
    attn_wsum<0, 128><<<dim3(256), blk, 0, stream>>>(score_w, owhi, owlo, senthi, sentlo);

    // Sentence input gates: dual-direction, M=256, N=768 -> grid (6, 4).
    const long XDS = 16L * 16 * 768;
    gemm_d<3, 0><<<dim3(6, 4), blk, 0, stream>>>(
        senthi, sentlo, S0HI, S0LO, S1HI, S1LO, s_bih_f, s_bih_b,
        xp_s, 768, XDS, nullptr, nullptr, 0, 15, 2);

    // Sentence BiGRU: 16 seqs/dir, T=16; 2 seqs/WG -> grid 16.
    gru2<<<dim3(16), dim3(512), 0, stream>>>(
        xp_s, HS0, HS1, s_bhh_f, s_bhh_b, sstate, oshi, oslo,
        16, 0, 15, 8, 16);

    // Sentence attention -> d_out (16 x 512 fp32). M=256, N=512 -> (4, 2).
    gemm_d<2, 1><<<dim3(4, 2), blk, 0, stream>>>(
        oshi, oslo, SAHI, SALO, SAHI, SALO, s_attn_b, s_attn_b,
        nullptr, 0, 0, score_s, s_ctx, 0, 0, 0);
    attn_wsum<1, 16><<<dim3(16), blk, 0, stream>>>(score_s, oshi, oslo, d_out, nullptr);
}